// Round 7
// baseline (181.972 us; speedup 1.0000x reference)
//
#include <hip/hip_runtime.h>

typedef float f32x2 __attribute__((ext_vector_type(2)));
typedef float f32x4 __attribute__((ext_vector_type(4)));
typedef float f32x16 __attribute__((ext_vector_type(16)));
typedef short bf16x8 __attribute__((ext_vector_type(8)));
typedef unsigned u32x2 __attribute__((ext_vector_type(2)));
typedef unsigned short u16;

#define S_LEN 4096
#define DMODEL 1024
#define NH 16
#define DK 64

// 1/sqrt(64) * log2(e): softmax runs in base-2 domain
#define SCALE_Q 0.18033688f

static __device__ __forceinline__ u16 f2bf(float x) {
  union { float f; unsigned u; } v; v.f = x;
  unsigned r = v.u + 0x7fffu + ((v.u >> 16) & 1u);  // RNE
  return (u16)(r >> 16);
}

static __device__ __forceinline__ float bf2f(u16 x) {
  union { unsigned u; float f; } v; v.u = ((unsigned)x) << 16;
  return v.f;
}

#if __has_builtin(__builtin_amdgcn_exp2f)
#define EXP2F __builtin_amdgcn_exp2f
#else
#define EXP2F exp2f
#endif

static __device__ __forceinline__ unsigned pkbf(float lo, float hi) {
  unsigned r;
  asm("v_cvt_pk_bf16_f32 %0, %1, %2" : "=v"(r) : "v"(lo), "v"(hi));
  return r;
}

static __device__ __forceinline__ void plswap(unsigned& a, unsigned& b, int hi) {
#if __has_builtin(__builtin_amdgcn_permlane32_swap)
  u32x2 r = __builtin_amdgcn_permlane32_swap(a, b, false, false);
  a = r.x; b = r.y;
  (void)hi;
#else
  unsigned ax = __shfl_xor(a, 32), bx = __shfl_xor(b, 32);
  unsigned na = hi ? bx : a;
  unsigned nb = hi ? b : ax;
  a = na; b = nb;
#endif
}

static __device__ __forceinline__ void gload16(const void* g, void* l) {
  void* gg = (void*)g;
  __builtin_amdgcn_global_load_lds(
      (__attribute__((address_space(1))) void*)gg,
      (__attribute__((address_space(3))) void*)l, 16, 0, 0);
}

// ---------------------------------------------------------------------------
// W (K,N) f32 -> Wt (N,K) bf16
// ---------------------------------------------------------------------------
__global__ __launch_bounds__(256) void wcast_t(const float* __restrict__ W,
                                               u16* __restrict__ Wt) {
  __shared__ float t[32][33];
  const int x = threadIdx.x, y = threadIdx.y;
  const int n0 = blockIdx.x * 32, k0 = blockIdx.y * 32;
#pragma unroll
  for (int i = 0; i < 4; ++i)
    t[y + 8 * i][x] = W[(size_t)(k0 + y + 8 * i) * DMODEL + n0 + x];
  __syncthreads();
#pragma unroll
  for (int i = 0; i < 4; ++i)
    Wt[(size_t)(n0 + y + 8 * i) * DMODEL + k0 + x] = f2bf(t[x][y + 8 * i]);
}

// ---------------------------------------------------------------------------
// f32 -> bf16 elementwise (8 elems/thread, 16B stores)
// ---------------------------------------------------------------------------
__global__ __launch_bounds__(256) void castbf(const float* __restrict__ in,
                                              u16* __restrict__ out, int n8) {
  int i = blockIdx.x * 256 + threadIdx.x;
  const int stride = gridDim.x * 256;
  for (; i < n8; i += stride) {
    float4 a = ((const float4*)in)[2 * i];
    float4 b = ((const float4*)in)[2 * i + 1];
    union { ushort4 u[2]; int4 q; } t;
    t.u[0].x = f2bf(a.x); t.u[0].y = f2bf(a.y);
    t.u[0].z = f2bf(a.z); t.u[0].w = f2bf(a.w);
    t.u[1].x = f2bf(b.x); t.u[1].y = f2bf(b.y);
    t.u[1].z = f2bf(b.z); t.u[1].w = f2bf(b.w);
    ((int4*)out)[i] = t.q;
  }
}

// ---------------------------------------------------------------------------
// pgemm: C(4096,1024) = A(4096,1024)bf16 @ Wt^T + bias, m97 128x128 tile.
// ---------------------------------------------------------------------------
template <int MODE>
__global__ __launch_bounds__(256) void pgemm(const u16* __restrict__ Abase,
                                             const u16* __restrict__ Btbase,
                                             const float* __restrict__ bq,
                                             const float* __restrict__ bk,
                                             const float* __restrict__ bv,
                                             void* __restrict__ outbase) {
  __shared__ __align__(16) char Al[16384];   // [128][128B] linear, XOR-swizzled
  __shared__ __align__(16) char Bl[16384];
  const int nblk = gridDim.x, cpx = nblk >> 3;
  const int b0 = blockIdx.x;
  const int bid = (b0 & 7) * cpx + (b0 >> 3);   // XCD swizzle (nblk%8==0)
  const int z = (MODE == 0) ? (bid >> 8) : 0;
  const int rem = bid & 255;
  const int nb = rem & 7, mb = rem >> 3;
  const int m0 = mb * 128, n0 = nb * 128;
  const int tid = threadIdx.x, lane = tid & 63, wid = tid >> 6;
  const int gq = lane >> 4, c16 = lane & 15;
  const int wm = (wid >> 1) * 64, wn = (wid & 1) * 64;
  const char* Ab = (const char*)(Abase + (size_t)z * S_LEN * DMODEL);
  const char* Bb = (const char*)(Btbase + (size_t)z * DMODEL * DMODEL);
  const float* bias = (z == 0) ? bq : (z == 1 ? bk : bv);
  const float scale = (MODE == 0 && z == 0) ? SCALE_Q : 1.0f;

  f32x4 acc[4][4] = {};

  for (int kt = 0; kt < 16; ++kt) {
    const int kb = kt * 128;
#pragma unroll
    for (int p = 0; p < 4; ++p) {
      int lin = p * 4096 + tid * 16;
      int row = lin >> 7;
      int colg = (lin & 127) ^ ((row & 7) << 4);
      gload16(Ab + (size_t)(m0 + row) * 2048 + kb + colg,
              Al + p * 4096 + wid * 1024);
    }
#pragma unroll
    for (int p = 0; p < 4; ++p) {
      int lin = p * 4096 + tid * 16;
      int row = lin >> 7;
      int colg = (lin & 127) ^ ((row & 7) << 4);
      gload16(Bb + (size_t)(n0 + row) * 2048 + kb + colg,
              Bl + p * 4096 + wid * 1024);
    }
    __syncthreads();
#pragma unroll
    for (int kk = 0; kk < 2; ++kk) {
      bf16x8 a[4], b[4];
#pragma unroll
      for (int m = 0; m < 4; ++m) {
        int row = wm + m * 16 + c16;
        a[m] = *(const bf16x8*)(Al + row * 128 +
                                ((kk * 64 + gq * 16) ^ ((row & 7) << 4)));
      }
#pragma unroll
      for (int n = 0; n < 4; ++n) {
        int row = wn + n * 16 + c16;
        b[n] = *(const bf16x8*)(Bl + row * 128 +
                                ((kk * 64 + gq * 16) ^ ((row & 7) << 4)));
      }
#pragma unroll
      for (int m = 0; m < 4; ++m)
#pragma unroll
        for (int n = 0; n < 4; ++n)
          acc[m][n] =
              __builtin_amdgcn_mfma_f32_16x16x32_bf16(a[m], b[n], acc[m][n], 0, 0, 0);
    }
    __syncthreads();
  }

#pragma unroll
  for (int m = 0; m < 4; ++m) {
#pragma unroll
    for (int n = 0; n < 4; ++n) {
      const int row = m0 + wm + m * 16 + gq * 4;
      const int col = n0 + wn + n * 16 + c16;
      const float bb = bias[col];
      if (MODE == 1) {
        float* of = (float*)outbase;
#pragma unroll
        for (int j = 0; j < 4; ++j)
          of[(size_t)(row + j) * DMODEL + col] = acc[m][n][j] + bb;
      } else if (z == 2) {
        // V: (H,64,S) transposed; 4 consecutive s -> one 8B store
        u16* ov = (u16*)outbase + (size_t)2 * S_LEN * DMODEL;
        ushort4 u;
        u.x = f2bf(acc[m][n][0] + bb);
        u.y = f2bf(acc[m][n][1] + bb);
        u.z = f2bf(acc[m][n][2] + bb);
        u.w = f2bf(acc[m][n][3] + bb);
        *(ushort4*)(ov + ((size_t)(col >> 6) * DK + (col & 63)) * S_LEN + row) = u;
      } else {
        u16* oq = (u16*)outbase + (size_t)z * S_LEN * DMODEL;
#pragma unroll
        for (int j = 0; j < 4; ++j)
          oq[((size_t)(col >> 6) * S_LEN + row + j) * DK + (col & 63)] =
              f2bf((acc[m][n][j] + bb) * scale);
      }
    }
  }
}

// ---------------------------------------------------------------------------
// Flash attention, swapped-QK^T, fixed-max base-2 softmax, KV-split x4.
// 512-thread blocks (8 waves x 32 q-rows = 256 q-rows/block), grid 1024
// (16h x 16qblk x 4kv) -> exactly 4 blocks/CU = 32 waves/CU (LDS 4x32KB=128K,
// VGPR 64 -> both fit). 16 KV-tiles of 64 keys per block.
// ---------------------------------------------------------------------------
__global__ __launch_bounds__(512) void attn2(const u16* __restrict__ q,
                                             const u16* __restrict__ k,
                                             const u16* __restrict__ vt,
                                             u16* __restrict__ Opart,
                                             float* __restrict__ Lpart) {
  __shared__ __align__(16) char smem[32768];  // 2 bufs x (K 8KB + V^T 8KB)
  const int bid0 = blockIdx.x;
  const int bid = (bid0 & 7) * 128 + (bid0 >> 3);  // XCD swizzle, 1024%8==0
  const int h = bid >> 6;
  const int kvh = (bid >> 4) & 3;
  const int qblk = bid & 15;
  const int tid = threadIdx.x;
  const int wid = tid >> 6, lane = tid & 63;
  const int l31 = lane & 31, hi = lane >> 5;

  const char* kpb = (const char*)k + (size_t)h * S_LEN * (DK * 2);
  const char* vtb = (const char*)vt + (size_t)h * DK * (S_LEN * 2);

  // Q B-fragments: col=q=lane&31, kdim d = 16*dt + 8*hi + j
  const int q0w = qblk * 256 + wid * 32;
  const u16* qrow = q + ((size_t)h * S_LEN + q0w + l31) * DK;
  bf16x8 qf[4];
#pragma unroll
  for (int dt = 0; dt < 4; ++dt)
    qf[dt] = *(const bf16x8*)(qrow + dt * 16 + hi * 8);

  f32x16 o0 = {}, o1 = {};   // O^T[d,q]: o0 = d 0..31, o1 = d 32..63
  f32x2 lacc2 = {0.f, 0.f};

  const int woff = wid << 10;     // each wave stages a contiguous 1KB chunk
  const int kt0 = kvh * 16;       // 16 tiles per quarter
  const int kt1 = kt0 + 16;

  // loop-invariant per-lane ds-read byte offsets (swizzled)
  const int swz = (l31 & 7) << 4;
  int dsa[4];
#pragma unroll
  for (int dt = 0; dt < 4; ++dt)
    dsa[dt] = (l31 << 7) + ((dt * 32 + hi * 16) ^ swz);

  // induction global staging pointers (1 K-load + 1 V-load per thread)
  const int lin = tid * 16;                       // 0..8176, covers 8KB
  const int sw = lin ^ (((lin >> 7) & 7) << 4);
  const char* gk = kpb + (size_t)kt0 * 8192 + sw;
  const char* gv = vtb + (size_t)(lin >> 7) * 8192 + (size_t)kt0 * 128 + (sw & 127);

  // prologue: stage tile kt0 into buf0
  gload16(gk, smem + woff);          gk += 8192;
  gload16(gv, smem + 8192 + woff);   gv += 128;
  __syncthreads();

  auto body = [&](const int CUR, const int NXT, bool doStage) {
    if (doStage) {
      gload16(gk, smem + NXT + woff);          gk += 8192;
      gload16(gv, smem + NXT + 8192 + woff);   gv += 128;
    }
    const char* kb = smem + CUR;
    const char* vb = smem + CUR + 8192;

    // QK^T swapped: st[k,q], A=K (row=key), B=Q (col=q)
    f32x16 st0 = {}, st1 = {};
    __builtin_amdgcn_s_setprio(1);
#pragma unroll
    for (int dt = 0; dt < 4; ++dt) {
      bf16x8 k0 = *(const bf16x8*)(kb + dsa[dt]);
      bf16x8 k1 = *(const bf16x8*)(kb + 4096 + dsa[dt]);
      st0 = __builtin_amdgcn_mfma_f32_32x32x16_bf16(k0, qf[dt], st0, 0, 0, 0);
      st1 = __builtin_amdgcn_mfma_f32_32x32x16_bf16(k1, qf[dt], st1, 0, 0, 0);
    }
    __builtin_amdgcn_s_setprio(0);

    // fixed-max base-2 softmax fused with bf16 pack: w[i]=pk(exp2,exp2)
    unsigned w0[8], w1[8];
    f32x2 s2 = {0.f, 0.f};
#pragma unroll
    for (int i = 0; i < 8; ++i) {
      float a0 = EXP2F(st0[2 * i]), a1 = EXP2F(st0[2 * i + 1]);
      f32x2 t = {a0, a1}; s2 += t;
      w0[i] = pkbf(a0, a1);
    }
#pragma unroll
    for (int i = 0; i < 8; ++i) {
      float a0 = EXP2F(st1[2 * i]), a1 = EXP2F(st1[2 * i + 1]);
      f32x2 t = {a0, a1}; s2 += t;
      w1[i] = pkbf(a0, a1);
    }
    lacc2 += s2;

    // P^T fragments: permlane32_swap pairs (w[i], w[i+2])
    union UF { unsigned w[4]; bf16x8 v; };
    UF f[4];
#pragma unroll
    for (int g = 0; g < 2; ++g) {
#pragma unroll
      for (int j = 0; j < 2; ++j) {
        unsigned a = w0[4 * g + j], b = w0[4 * g + j + 2];
        plswap(a, b, hi);
        f[g].w[j] = a; f[g].w[j + 2] = b;
        unsigned c = w1[4 * g + j], d = w1[4 * g + j + 2];
        plswap(c, d, hi);
        f[2 + g].w[j] = c; f[2 + g].w[j + 2] = d;
      }
    }

    // PV: O^T[d,q] += V^T[d,k] P^T[k,q]
    __builtin_amdgcn_s_setprio(1);
#pragma unroll
    for (int kt2 = 0; kt2 < 4; ++kt2) {
      bf16x8 v0 = *(const bf16x8*)(vb + dsa[kt2]);
      bf16x8 v1 = *(const bf16x8*)(vb + 4096 + dsa[kt2]);
      o0 = __builtin_amdgcn_mfma_f32_32x32x16_bf16(v0, f[kt2].v, o0, 0, 0, 0);
      o1 = __builtin_amdgcn_mfma_f32_32x32x16_bf16(v1, f[kt2].v, o1, 0, 0, 0);
    }
    __builtin_amdgcn_s_setprio(0);

    __syncthreads();
  };

  for (int kt = kt0; kt < kt1; kt += 2) {
    body(0, 16384, kt + 1 < kt1);
    body(16384, 0, kt + 2 < kt1);
  }

  // epilogue: store unnormalized partial O^T (bf16) + partial l (f32)
  const float lacc = lacc2.x + lacc2.y;
  const float lrow = lacc + __shfl_xor(lacc, 32);
  u16* Ob = Opart + ((((size_t)kvh * NH + h) * S_LEN) + q0w + l31) * DK;
#pragma unroll
  for (int g = 0; g < 4; ++g) {
    ushort4 u0, u1;
    u0.x = f2bf(o0[g * 4 + 0]); u0.y = f2bf(o0[g * 4 + 1]);
    u0.z = f2bf(o0[g * 4 + 2]); u0.w = f2bf(o0[g * 4 + 3]);
    *(ushort4*)(Ob + 8 * g + 4 * hi) = u0;
    u1.x = f2bf(o1[g * 4 + 0]); u1.y = f2bf(o1[g * 4 + 1]);
    u1.z = f2bf(o1[g * 4 + 2]); u1.w = f2bf(o1[g * 4 + 3]);
    *(ushort4*)(Ob + 32 + 8 * g + 4 * hi) = u1;
  }
  Lpart[((size_t)kvh * NH + h) * S_LEN + q0w + l31] = lrow;
}

// ---------------------------------------------------------------------------
// combine: comb[q][h*64+d] = sum_kv(O_kv) / sum_kv(l_kv), bf16 partials (x4)
// ---------------------------------------------------------------------------
__global__ __launch_bounds__(256) void combine(const u16* __restrict__ Op,
                                               const float* __restrict__ Lp,
                                               u16* __restrict__ comb) {
  const int id = blockIdx.x * 256 + threadIdx.x;   // 1M threads
  const int h = id >> 16;
  const int rem = id & 65535;
  const int qv = rem >> 4;
  const int d4 = (rem & 15) << 2;
  const size_t str = (size_t)NH * S_LEN * DK;
  const size_t base = (((size_t)h * S_LEN) + qv) * DK + d4;
  float o0 = 0.f, o1 = 0.f, o2 = 0.f, o3 = 0.f, l = 0.f;
#pragma unroll
  for (int kv = 0; kv < 4; ++kv) {
    ushort4 u = *(const ushort4*)(Op + kv * str + base);
    o0 += bf2f(u.x); o1 += bf2f(u.y); o2 += bf2f(u.z); o3 += bf2f(u.w);
    l += Lp[(size_t)kv * NH * S_LEN + (size_t)h * S_LEN + qv];
  }
  const float inv = 1.f / l;
  ushort4 u;
  u.x = f2bf(o0 * inv);
  u.y = f2bf(o1 * inv);
  u.z = f2bf(o2 * inv);
  u.w = f2bf(o3 * inv);
  *(ushort4*)(comb + (size_t)qv * DMODEL + h * DK + d4) = u;
}

// ---------------------------------------------------------------------------
extern "C" void kernel_launch(void* const* d_in, const int* in_sizes, int n_in,
                              void* d_out, int out_size, void* d_ws, size_t ws_size,
                              hipStream_t stream) {
  (void)in_sizes; (void)n_in; (void)out_size; (void)ws_size;
  const float* Q   = (const float*)d_in[0];
  const float* K   = (const float*)d_in[1];
  const float* V   = (const float*)d_in[2];
  const float* W_Q = (const float*)d_in[3];
  const float* b_Q = (const float*)d_in[4];
  const float* W_K = (const float*)d_in[5];
  const float* b_K = (const float*)d_in[6];
  const float* W_V = (const float*)d_in[7];
  const float* b_V = (const float*)d_in[8];
  const float* W_O = (const float*)d_in[9];
  const float* b_O = (const float*)d_in[10];
  float* out = (float*)d_out;

  char* ws = (char*)d_ws;
  const size_t MB = 1024 * 1024;
  u16* WtQ = (u16*)ws;                        // 4 x 2MB = [0, 8MB)
  u16* Qbf = (u16*)(ws + 8 * MB);             // 3 x 8MB = [8, 32MB); dead after pgemm<0>
  u16* Opart = (u16*)(ws + 8 * MB);           // 4 x 8MB = [8, 40MB) bf16 (overlays Qbf)
  u16* qp   = (u16*)(ws + 40 * MB);           // (H,S,64)  [40,48)
  u16* kp   = qp + (size_t)S_LEN * DMODEL;    //           [48,56)
  u16* vtp  = kp + (size_t)S_LEN * DMODEL;    // (H,64,S)  [56,64)
  u16* comb = vtp + (size_t)S_LEN * DMODEL;   // (S,1024)  [64,72)
  float* Lpart = (float*)(ws + 72 * MB);      // 4 x (H,S) f32 = 1MB [72,73)

  dim3 tb(32, 8);
  dim3 tg(32, 32);
  wcast_t<<<tg, tb, 0, stream>>>(W_Q, WtQ);
  wcast_t<<<tg, tb, 0, stream>>>(W_K, WtQ + (size_t)DMODEL * DMODEL);
  wcast_t<<<tg, tb, 0, stream>>>(W_V, WtQ + (size_t)2 * DMODEL * DMODEL);
  wcast_t<<<tg, tb, 0, stream>>>(W_O, WtQ + (size_t)3 * DMODEL * DMODEL);

  const int n8 = S_LEN * DMODEL / 8;
  castbf<<<2048, 256, 0, stream>>>(Q, Qbf, n8);
  castbf<<<2048, 256, 0, stream>>>(K, Qbf + (size_t)S_LEN * DMODEL, n8);
  castbf<<<2048, 256, 0, stream>>>(V, Qbf + (size_t)2 * S_LEN * DMODEL, n8);

  pgemm<0><<<768, 256, 0, stream>>>(Qbf, WtQ, b_Q, b_K, b_V, qp);

  attn2<<<1024, 512, 0, stream>>>(qp, kp, vtp, Opart, Lpart);
  combine<<<4096, 256, 0, stream>>>(Opart, Lpart, comb);

  pgemm<1><<<256, 256, 0, stream>>>(comb, WtQ + (size_t)3 * DMODEL * DMODEL,
                                    b_O, b_O, b_O, out);
}

// Round 8
// 168.746 us; speedup vs baseline: 1.0784x; 1.0784x over previous
//
#include <hip/hip_runtime.h>

typedef float f32x2 __attribute__((ext_vector_type(2)));
typedef float f32x4 __attribute__((ext_vector_type(4)));
typedef float f32x16 __attribute__((ext_vector_type(16)));
typedef short bf16x8 __attribute__((ext_vector_type(8)));
typedef unsigned u32x2 __attribute__((ext_vector_type(2)));
typedef unsigned short u16;

#define S_LEN 4096
#define DMODEL 1024
#define NH 16
#define DK 64

// 1/sqrt(64) * log2(e): softmax runs in base-2 domain
#define SCALE_Q 0.18033688f

static __device__ __forceinline__ u16 f2bf(float x) {
  union { float f; unsigned u; } v; v.f = x;
  unsigned r = v.u + 0x7fffu + ((v.u >> 16) & 1u);  // RNE
  return (u16)(r >> 16);
}

static __device__ __forceinline__ float bf2f(u16 x) {
  union { unsigned u; float f; } v; v.u = ((unsigned)x) << 16;
  return v.f;
}

#if __has_builtin(__builtin_amdgcn_exp2f)
#define EXP2F __builtin_amdgcn_exp2f
#else
#define EXP2F exp2f
#endif

static __device__ __forceinline__ unsigned pkbf(float lo, float hi) {
  unsigned r;
  asm("v_cvt_pk_bf16_f32 %0, %1, %2" : "=v"(r) : "v"(lo), "v"(hi));
  return r;
}

static __device__ __forceinline__ void plswap(unsigned& a, unsigned& b, int hi) {
#if __has_builtin(__builtin_amdgcn_permlane32_swap)
  u32x2 r = __builtin_amdgcn_permlane32_swap(a, b, false, false);
  a = r.x; b = r.y;
  (void)hi;
#else
  unsigned ax = __shfl_xor(a, 32), bx = __shfl_xor(b, 32);
  unsigned na = hi ? bx : a;
  unsigned nb = hi ? b : ax;
  a = na; b = nb;
#endif
}

static __device__ __forceinline__ void gload16(const void* g, void* l) {
  void* gg = (void*)g;
  __builtin_amdgcn_global_load_lds(
      (__attribute__((address_space(1))) void*)gg,
      (__attribute__((address_space(3))) void*)l, 16, 0, 0);
}

// ---------------------------------------------------------------------------
// 4x W (K,N) f32 -> Wt (N,K) bf16, one launch (blockIdx.z selects weight)
// ---------------------------------------------------------------------------
__global__ __launch_bounds__(256) void wcast4(const float* __restrict__ W0,
                                              const float* __restrict__ W1,
                                              const float* __restrict__ W2,
                                              const float* __restrict__ W3,
                                              u16* __restrict__ Wt) {
  __shared__ float t[32][33];
  const int z = blockIdx.z;
  const float* W = (z == 0) ? W0 : (z == 1) ? W1 : (z == 2) ? W2 : W3;
  u16* dst = Wt + (size_t)z * DMODEL * DMODEL;
  const int x = threadIdx.x, y = threadIdx.y;
  const int n0 = blockIdx.x * 32, k0 = blockIdx.y * 32;
#pragma unroll
  for (int i = 0; i < 4; ++i)
    t[y + 8 * i][x] = W[(size_t)(k0 + y + 8 * i) * DMODEL + n0 + x];
  __syncthreads();
#pragma unroll
  for (int i = 0; i < 4; ++i)
    dst[(size_t)(n0 + y + 8 * i) * DMODEL + k0 + x] = f2bf(t[x][y + 8 * i]);
}

// ---------------------------------------------------------------------------
// 3x f32 -> bf16 elementwise, one launch (blockIdx.x>>10 selects source)
// ---------------------------------------------------------------------------
__global__ __launch_bounds__(256) void castbf3(const float* __restrict__ A,
                                               const float* __restrict__ B,
                                               const float* __restrict__ C,
                                               u16* __restrict__ out) {
  const int z = blockIdx.x >> 10;
  const int b = blockIdx.x & 1023;
  const float* src = (z == 0) ? A : (z == 1) ? B : C;
  u16* dst = out + (size_t)z * S_LEN * DMODEL;
  const int n8 = S_LEN * DMODEL / 8;
  for (int i = b * 256 + threadIdx.x; i < n8; i += 1024 * 256) {
    float4 a = ((const float4*)src)[2 * i];
    float4 c = ((const float4*)src)[2 * i + 1];
    union { ushort4 u[2]; int4 q; } t;
    t.u[0].x = f2bf(a.x); t.u[0].y = f2bf(a.y);
    t.u[0].z = f2bf(a.z); t.u[0].w = f2bf(a.w);
    t.u[1].x = f2bf(c.x); t.u[1].y = f2bf(c.y);
    t.u[1].z = f2bf(c.z); t.u[1].w = f2bf(c.w);
    ((int4*)dst)[i] = t.q;
  }
}

// ---------------------------------------------------------------------------
// pgemm: C(4096,1024) = A(4096,1024)bf16 @ Wt^T + bias, m97 128x128 tile.
// ---------------------------------------------------------------------------
template <int MODE>
__global__ __launch_bounds__(256) void pgemm(const u16* __restrict__ Abase,
                                             const u16* __restrict__ Btbase,
                                             const float* __restrict__ bq,
                                             const float* __restrict__ bk,
                                             const float* __restrict__ bv,
                                             void* __restrict__ outbase) {
  __shared__ __align__(16) char Al[16384];   // [128][128B] linear, XOR-swizzled
  __shared__ __align__(16) char Bl[16384];
  const int nblk = gridDim.x, cpx = nblk >> 3;
  const int b0 = blockIdx.x;
  const int bid = (b0 & 7) * cpx + (b0 >> 3);   // XCD swizzle (nblk%8==0)
  const int z = (MODE == 0) ? (bid >> 8) : 0;
  const int rem = bid & 255;
  const int nb = rem & 7, mb = rem >> 3;
  const int m0 = mb * 128, n0 = nb * 128;
  const int tid = threadIdx.x, lane = tid & 63, wid = tid >> 6;
  const int gq = lane >> 4, c16 = lane & 15;
  const int wm = (wid >> 1) * 64, wn = (wid & 1) * 64;
  const char* Ab = (const char*)(Abase + (size_t)z * S_LEN * DMODEL);
  const char* Bb = (const char*)(Btbase + (size_t)z * DMODEL * DMODEL);
  const float* bias = (z == 0) ? bq : (z == 1 ? bk : bv);
  const float scale = (MODE == 0 && z == 0) ? SCALE_Q : 1.0f;

  f32x4 acc[4][4] = {};

  for (int kt = 0; kt < 16; ++kt) {
    const int kb = kt * 128;
#pragma unroll
    for (int p = 0; p < 4; ++p) {
      int lin = p * 4096 + tid * 16;
      int row = lin >> 7;
      int colg = (lin & 127) ^ ((row & 7) << 4);
      gload16(Ab + (size_t)(m0 + row) * 2048 + kb + colg,
              Al + p * 4096 + wid * 1024);
    }
#pragma unroll
    for (int p = 0; p < 4; ++p) {
      int lin = p * 4096 + tid * 16;
      int row = lin >> 7;
      int colg = (lin & 127) ^ ((row & 7) << 4);
      gload16(Bb + (size_t)(n0 + row) * 2048 + kb + colg,
              Bl + p * 4096 + wid * 1024);
    }
    __syncthreads();
#pragma unroll
    for (int kk = 0; kk < 2; ++kk) {
      bf16x8 a[4], b[4];
#pragma unroll
      for (int m = 0; m < 4; ++m) {
        int row = wm + m * 16 + c16;
        a[m] = *(const bf16x8*)(Al + row * 128 +
                                ((kk * 64 + gq * 16) ^ ((row & 7) << 4)));
      }
#pragma unroll
      for (int n = 0; n < 4; ++n) {
        int row = wn + n * 16 + c16;
        b[n] = *(const bf16x8*)(Bl + row * 128 +
                                ((kk * 64 + gq * 16) ^ ((row & 7) << 4)));
      }
#pragma unroll
      for (int m = 0; m < 4; ++m)
#pragma unroll
        for (int n = 0; n < 4; ++n)
          acc[m][n] =
              __builtin_amdgcn_mfma_f32_16x16x32_bf16(a[m], b[n], acc[m][n], 0, 0, 0);
    }
    __syncthreads();
  }

#pragma unroll
  for (int m = 0; m < 4; ++m) {
#pragma unroll
    for (int n = 0; n < 4; ++n) {
      const int row = m0 + wm + m * 16 + gq * 4;
      const int col = n0 + wn + n * 16 + c16;
      const float bb = bias[col];
      if (MODE == 1) {
        float* of = (float*)outbase;
#pragma unroll
        for (int j = 0; j < 4; ++j)
          of[(size_t)(row + j) * DMODEL + col] = acc[m][n][j] + bb;
      } else if (z == 2) {
        // V: (H,64,S) transposed; 4 consecutive s -> one 8B store
        u16* ov = (u16*)outbase + (size_t)2 * S_LEN * DMODEL;
        ushort4 u;
        u.x = f2bf(acc[m][n][0] + bb);
        u.y = f2bf(acc[m][n][1] + bb);
        u.z = f2bf(acc[m][n][2] + bb);
        u.w = f2bf(acc[m][n][3] + bb);
        *(ushort4*)(ov + ((size_t)(col >> 6) * DK + (col & 63)) * S_LEN + row) = u;
      } else {
        u16* oq = (u16*)outbase + (size_t)z * S_LEN * DMODEL;
#pragma unroll
        for (int j = 0; j < 4; ++j)
          oq[((size_t)(col >> 6) * S_LEN + row + j) * DK + (col & 63)] =
              f2bf((acc[m][n][j] + bb) * scale);
      }
    }
  }
}

// ---------------------------------------------------------------------------
// Flash attention, swapped-QK^T, fixed-max base-2 softmax, KV-split x2.
// 512-thread blocks (8 waves x 32 q-rows = 256 q-rows/block), grid 512.
// This round: counted-vmcnt double-barrier (no full drain) per tile:
//   stage(NXT) -> s_waitcnt vmcnt(2) -> s_barrier -> compute(CUR) -> s_barrier
// Staging issued at body t completes any time before body t+1's reads.
// ---------------------------------------------------------------------------
__global__ __launch_bounds__(512) void attn2(const u16* __restrict__ q,
                                             const u16* __restrict__ k,
                                             const u16* __restrict__ vt,
                                             u16* __restrict__ Opart,
                                             float* __restrict__ Lpart) {
  __shared__ __align__(16) char smem[32768];  // 2 bufs x (K 8KB + V^T 8KB)
  const int bid0 = blockIdx.x;
  const int bid = (bid0 & 7) * 64 + (bid0 >> 3);  // XCD swizzle, 512%8==0
  const int h = bid >> 5;
  const int kvh = (bid >> 4) & 1;
  const int qblk = bid & 15;
  const int tid = threadIdx.x;
  const int wid = tid >> 6, lane = tid & 63;
  const int l31 = lane & 31, hi = lane >> 5;

  const char* kpb = (const char*)k + (size_t)h * S_LEN * (DK * 2);
  const char* vtb = (const char*)vt + (size_t)h * DK * (S_LEN * 2);

  // Q B-fragments: col=q=lane&31, kdim d = 16*dt + 8*hi + j
  const int q0w = qblk * 256 + wid * 32;
  const u16* qrow = q + ((size_t)h * S_LEN + q0w + l31) * DK;
  bf16x8 qf[4];
#pragma unroll
  for (int dt = 0; dt < 4; ++dt)
    qf[dt] = *(const bf16x8*)(qrow + dt * 16 + hi * 8);

  f32x16 o0 = {}, o1 = {};   // O^T[d,q]: o0 = d 0..31, o1 = d 32..63
  f32x2 lacc2 = {0.f, 0.f};

  const int woff = wid << 10;     // each wave stages a contiguous 1KB chunk
  const int kt0 = kvh * 32;       // 32 tiles per half
  const int kt1 = kt0 + 32;

  // loop-invariant per-lane ds-read byte offsets (swizzled)
  const int swz = (l31 & 7) << 4;
  int dsa[4];
#pragma unroll
  for (int dt = 0; dt < 4; ++dt)
    dsa[dt] = (l31 << 7) + ((dt * 32 + hi * 16) ^ swz);

  // induction global staging pointers (1 K-load + 1 V-load per thread)
  const int lin = tid * 16;                       // 0..8176, covers 8KB
  const int sw = lin ^ (((lin >> 7) & 7) << 4);
  const char* gk = kpb + (size_t)kt0 * 8192 + sw;
  const char* gv = vtb + (size_t)(lin >> 7) * 8192 + (size_t)kt0 * 128 + (sw & 127);

  // prologue: stage tile kt0 into buf0
  gload16(gk, smem + woff);          gk += 8192;
  gload16(gv, smem + 8192 + woff);   gv += 128;

  auto body = [&](const int CUR, const int NXT, bool doStage) {
    if (doStage) {
      gload16(gk, smem + NXT + woff);          gk += 8192;
      gload16(gv, smem + NXT + 8192 + woff);   gv += 128;
      asm volatile("s_waitcnt vmcnt(2)" ::: "memory");  // CUR staged; NXT in flight
    } else {
      asm volatile("s_waitcnt vmcnt(0)" ::: "memory");
    }
    __builtin_amdgcn_s_barrier();   // all waves: CUR data ready

    const char* kb = smem + CUR;
    const char* vb = smem + CUR + 8192;

    // QK^T swapped: st[k,q], A=K (row=key), B=Q (col=q)
    f32x16 st0 = {}, st1 = {};
    __builtin_amdgcn_s_setprio(1);
#pragma unroll
    for (int dt = 0; dt < 4; ++dt) {
      bf16x8 k0 = *(const bf16x8*)(kb + dsa[dt]);
      bf16x8 k1 = *(const bf16x8*)(kb + 4096 + dsa[dt]);
      st0 = __builtin_amdgcn_mfma_f32_32x32x16_bf16(k0, qf[dt], st0, 0, 0, 0);
      st1 = __builtin_amdgcn_mfma_f32_32x32x16_bf16(k1, qf[dt], st1, 0, 0, 0);
    }
    __builtin_amdgcn_s_setprio(0);

    // fixed-max base-2 softmax fused with bf16 pack: w[i]=pk(exp2,exp2)
    unsigned w0[8], w1[8];
    f32x2 s2 = {0.f, 0.f};
#pragma unroll
    for (int i = 0; i < 8; ++i) {
      float a0 = EXP2F(st0[2 * i]), a1 = EXP2F(st0[2 * i + 1]);
      f32x2 t = {a0, a1}; s2 += t;
      w0[i] = pkbf(a0, a1);
    }
#pragma unroll
    for (int i = 0; i < 8; ++i) {
      float a0 = EXP2F(st1[2 * i]), a1 = EXP2F(st1[2 * i + 1]);
      f32x2 t = {a0, a1}; s2 += t;
      w1[i] = pkbf(a0, a1);
    }
    lacc2 += s2;

    // P^T fragments: permlane32_swap pairs (w[i], w[i+2])
    union UF { unsigned w[4]; bf16x8 v; };
    UF f[4];
#pragma unroll
    for (int g = 0; g < 2; ++g) {
#pragma unroll
      for (int j = 0; j < 2; ++j) {
        unsigned a = w0[4 * g + j], b = w0[4 * g + j + 2];
        plswap(a, b, hi);
        f[g].w[j] = a; f[g].w[j + 2] = b;
        unsigned c = w1[4 * g + j], d = w1[4 * g + j + 2];
        plswap(c, d, hi);
        f[2 + g].w[j] = c; f[2 + g].w[j + 2] = d;
      }
    }

    // PV: O^T[d,q] += V^T[d,k] P^T[k,q]
    __builtin_amdgcn_s_setprio(1);
#pragma unroll
    for (int kt2 = 0; kt2 < 4; ++kt2) {
      bf16x8 v0 = *(const bf16x8*)(vb + dsa[kt2]);
      bf16x8 v1 = *(const bf16x8*)(vb + 4096 + dsa[kt2]);
      o0 = __builtin_amdgcn_mfma_f32_32x32x16_bf16(v0, f[kt2].v, o0, 0, 0, 0);
      o1 = __builtin_amdgcn_mfma_f32_32x32x16_bf16(v1, f[kt2].v, o1, 0, 0, 0);
    }
    __builtin_amdgcn_s_setprio(0);

    __builtin_amdgcn_s_barrier();   // all waves done reading CUR
  };

  for (int kt = kt0; kt < kt1; kt += 2) {
    body(0, 16384, kt + 1 < kt1);
    body(16384, 0, kt + 2 < kt1);
  }

  // epilogue: store unnormalized partial O^T (bf16) + partial l (f32)
  const float lacc = lacc2.x + lacc2.y;
  const float lrow = lacc + __shfl_xor(lacc, 32);
  u16* Ob = Opart + ((((size_t)kvh * NH + h) * S_LEN) + q0w + l31) * DK;
#pragma unroll
  for (int g = 0; g < 4; ++g) {
    ushort4 u0, u1;
    u0.x = f2bf(o0[g * 4 + 0]); u0.y = f2bf(o0[g * 4 + 1]);
    u0.z = f2bf(o0[g * 4 + 2]); u0.w = f2bf(o0[g * 4 + 3]);
    *(ushort4*)(Ob + 8 * g + 4 * hi) = u0;
    u1.x = f2bf(o1[g * 4 + 0]); u1.y = f2bf(o1[g * 4 + 1]);
    u1.z = f2bf(o1[g * 4 + 2]); u1.w = f2bf(o1[g * 4 + 3]);
    *(ushort4*)(Ob + 32 + 8 * g + 4 * hi) = u1;
  }
  Lpart[((size_t)kvh * NH + h) * S_LEN + q0w + l31] = lrow;
}

// ---------------------------------------------------------------------------
// combine: comb[q][h*64+d] = sum_kv(O_kv) / sum_kv(l_kv), bf16 partials (x2)
// ---------------------------------------------------------------------------
__global__ __launch_bounds__(256) void combine(const u16* __restrict__ Op,
                                               const float* __restrict__ Lp,
                                               u16* __restrict__ comb) {
  const int id = blockIdx.x * 256 + threadIdx.x;   // 1M threads
  const int h = id >> 16;
  const int rem = id & 65535;
  const int qv = rem >> 4;
  const int d4 = (rem & 15) << 2;
  const size_t str = (size_t)NH * S_LEN * DK;
  const size_t base = (((size_t)h * S_LEN) + qv) * DK + d4;
  float o0 = 0.f, o1 = 0.f, o2 = 0.f, o3 = 0.f, l = 0.f;
#pragma unroll
  for (int kv = 0; kv < 2; ++kv) {
    ushort4 u = *(const ushort4*)(Op + kv * str + base);
    o0 += bf2f(u.x); o1 += bf2f(u.y); o2 += bf2f(u.z); o3 += bf2f(u.w);
    l += Lp[(size_t)kv * NH * S_LEN + (size_t)h * S_LEN + qv];
  }
  const float inv = 1.f / l;
  ushort4 u;
  u.x = f2bf(o0 * inv);
  u.y = f2bf(o1 * inv);
  u.z = f2bf(o2 * inv);
  u.w = f2bf(o3 * inv);
  *(ushort4*)(comb + (size_t)qv * DMODEL + h * DK + d4) = u;
}

// ---------------------------------------------------------------------------
extern "C" void kernel_launch(void* const* d_in, const int* in_sizes, int n_in,
                              void* d_out, int out_size, void* d_ws, size_t ws_size,
                              hipStream_t stream) {
  (void)in_sizes; (void)n_in; (void)out_size; (void)ws_size;
  const float* Q   = (const float*)d_in[0];
  const float* K   = (const float*)d_in[1];
  const float* V   = (const float*)d_in[2];
  const float* W_Q = (const float*)d_in[3];
  const float* b_Q = (const float*)d_in[4];
  const float* W_K = (const float*)d_in[5];
  const float* b_K = (const float*)d_in[6];
  const float* W_V = (const float*)d_in[7];
  const float* b_V = (const float*)d_in[8];
  const float* W_O = (const float*)d_in[9];
  const float* b_O = (const float*)d_in[10];
  float* out = (float*)d_out;

  char* ws = (char*)d_ws;
  const size_t MB = 1024 * 1024;
  u16* WtQ = (u16*)ws;                        // 4 x 2MB = [0, 8MB)
  u16* Qbf = (u16*)(ws + 8 * MB);             // 3 x 8MB = [8, 32MB); dead after pgemm<0>
  u16* Opart = (u16*)(ws + 8 * MB);           // 2 x 8MB = [8, 24MB) bf16 (overlays Qbf)
  u16* qp   = (u16*)(ws + 40 * MB);           // (H,S,64)  [40,48)
  u16* kp   = qp + (size_t)S_LEN * DMODEL;    //           [48,56)
  u16* vtp  = kp + (size_t)S_LEN * DMODEL;    // (H,64,S)  [56,64)
  u16* comb = vtp + (size_t)S_LEN * DMODEL;   // (S,1024)  [64,72)
  float* Lpart = (float*)(ws + 72 * MB);      // 2 x (H,S) f32 = 512KB

  dim3 tb(32, 8);
  dim3 tg4(32, 32, 4);
  wcast4<<<tg4, tb, 0, stream>>>(W_Q, W_K, W_V, W_O, WtQ);

  castbf3<<<3072, 256, 0, stream>>>(Q, K, V, Qbf);

  pgemm<0><<<768, 256, 0, stream>>>(Qbf, WtQ, b_Q, b_K, b_V, qp);

  attn2<<<512, 512, 0, stream>>>(qp, kp, vtp, Opart, Lpart);
  combine<<<4096, 256, 0, stream>>>(Opart, Lpart, comb);

  pgemm<1><<<256, 256, 0, stream>>>(comb, WtQ + (size_t)3 * DMODEL * DMODEL,
                                    b_O, b_O, b_O, out);
}